// Round 10
// baseline (213.209 us; speedup 1.0000x reference)
//
#include <hip/hip_runtime.h>

// GraphSAGE 2-layer encoder: binned-sort slack-bucket CSR (LDS atomics only),
// degree-banded node scheduling (pnode), bf16 activations, register-resident-B
// MFMA GEMMs, dual-output layer-2 GEMM, shfl-broadcast gathers with masked
// tail. d_out doubles as scratch (xb/ub). N=100000, E=1600000, D=128/128/64.

constexpr int TPB = 256;
constexpr int CAP = 64;    // neighbor slots per node; P(Poisson(16) >= 64) ~ 1e-20
constexpr int NBIN = 256;  // dst bins of 512 nodes (dst>>9)
constexpr int NBLKA = 512; // phase-A blocks

typedef __attribute__((ext_vector_type(8))) short bf16x8;
typedef __attribute__((ext_vector_type(4))) float f32x4;

// ---------- bf16 helpers ----------
static __device__ __forceinline__ unsigned short f2bf(float f) {
    unsigned int u = __float_as_uint(f);
    u += 0x7fffu + ((u >> 16) & 1u);   // round-to-nearest-even
    return (unsigned short)(u >> 16);
}
static __device__ __forceinline__ float bfe2f(short s) {
    return __uint_as_float(((unsigned int)(unsigned short)s) << 16);
}

// ================= binned counting sort (no global atomics) =================

// A1: per-block histogram of dst bins.
__global__ void binA_count(const int* __restrict__ dst, int* __restrict__ blockhist,
                           int E, int epb) {
    __shared__ int hist[NBIN];
    hist[threadIdx.x] = 0;
    __syncthreads();
    int e0 = blockIdx.x * epb, e1 = min(E, e0 + epb);
    for (int i = e0 + threadIdx.x; i < e1; i += TPB)
        atomicAdd(&hist[dst[i] >> 9], 1);
    __syncthreads();
    blockhist[threadIdx.x * NBLKA + blockIdx.x] = hist[threadIdx.x];
}

// A2a: bintotal[b] = sum over blocks.
__global__ void binA_total(const int* __restrict__ blockhist, int* __restrict__ bintotal) {
    __shared__ int s[TPB];
    int b = blockIdx.x;
    int sum = 0;
    for (int i = threadIdx.x; i < NBLKA; i += TPB) sum += blockhist[b * NBLKA + i];
    s[threadIdx.x] = sum;
    __syncthreads();
    for (int o = 128; o > 0; o >>= 1) {
        if (threadIdx.x < o) s[threadIdx.x] += s[threadIdx.x + o];
        __syncthreads();
    }
    if (threadIdx.x == 0) bintotal[b] = s[0];
}

// A2b: exclusive scan of bintotal -> binstart[0..NBIN], sentinel at NBIN.
__global__ void binA_scan(const int* __restrict__ bintotal, int* __restrict__ binstart) {
    __shared__ int s[NBIN];
    int t = threadIdx.x;
    s[t] = bintotal[t];
    __syncthreads();
    for (int o = 1; o < NBIN; o <<= 1) {
        int v = (t >= o) ? s[t - o] : 0;
        __syncthreads();
        s[t] += v;
        __syncthreads();
    }
    binstart[t] = t ? s[t - 1] : 0;
    if (t == NBIN - 1) binstart[NBIN] = s[NBIN - 1];
}

// A2c: per-(bin,block) scatter base = binstart[b] + prefix over blocks. 512 thr.
__global__ void binA_boff(const int* __restrict__ blockhist, const int* __restrict__ binstart,
                          int* __restrict__ boff) {
    __shared__ int s[NBLKA];
    int b = blockIdx.x, t = threadIdx.x;
    s[t] = blockhist[b * NBLKA + t];
    __syncthreads();
    for (int o = 1; o < NBLKA; o <<= 1) {
        int v = (t >= o) ? s[t - o] : 0;
        __syncthreads();
        s[t] += v;
        __syncthreads();
    }
    int excl = t ? s[t - 1] : 0;
    boff[b * NBLKA + t] = binstart[b] + excl;
}

// A3: scatter (src,dst) pairs into bin-sorted buffer at pre-reserved offsets.
__global__ void binA_scatter(const int* __restrict__ src, const int* __restrict__ dst,
                             const int* __restrict__ boff, int2* __restrict__ sorted,
                             int E, int epb) {
    __shared__ int base[NBIN];
    __shared__ int lcur[NBIN];
    int t = threadIdx.x, blk = blockIdx.x;
    base[t] = boff[t * NBLKA + blk];
    lcur[t] = 0;
    __syncthreads();
    int e0 = blk * epb, e1 = min(E, e0 + epb);
    for (int i = e0 + t; i < e1; i += TPB) {
        int d = dst[i];
        int b = d >> 9;
        int p = base[b] + atomicAdd(&lcur[b], 1);
        sorted[p] = make_int2(src[i], d);
    }
}

// B: one block per 512-node bin; LDS cursors; XCD-local nbrp writes.
// Also counting-sorts the bin's nodes by clamped degree -> pnode (pads -1),
// so gather waves serve degree-banded node groups (trip count ~ d, not max d).
__global__ void binB_build(const int2* __restrict__ sorted, const int* __restrict__ binstart,
                           int* __restrict__ cursor, int* __restrict__ nbrp,
                           int* __restrict__ pnode, int N) {
    __shared__ int lcur[512];
    __shared__ int hist[CAP + 1];
    int t = threadIdx.x, b = blockIdx.x;
    lcur[t] = 0;
    lcur[t + 256] = 0;
    if (t <= CAP) hist[t] = 0;
    __syncthreads();
    int lo = binstart[b], hi = binstart[b + 1];
    int node0 = b << 9;
    int cnt = min(512, N - node0);
    for (int i = lo + t; i < hi; i += TPB) {
        int2 e = sorted[i];
        int p = atomicAdd(&lcur[e.y - node0], 1);
        if (p < CAP) nbrp[(size_t)e.y * CAP + p] = e.x;
    }
    __syncthreads();
    for (int k = t; k < cnt; k += TPB) atomicAdd(&hist[min(lcur[k], CAP)], 1);
    __syncthreads();
    if (t == 0) {
        int run = 0;
        for (int q = 0; q <= CAP; q++) { int c = hist[q]; hist[q] = run; run += c; }
    }
    __syncthreads();
    for (int k = t; k < cnt; k += TPB) {
        int node = node0 + k;
        cursor[node] = lcur[k];
        int r = atomicAdd(&hist[min(lcur[k], CAP)], 1);
        pnode[(b << 9) + r] = node;
    }
    for (int k = cnt + t; k < 512; k += TPB) pnode[(b << 9) + k] = -1;
}

// ---------- fp32 -> bf16 cast ----------
__global__ void cast_bf16_kernel(const float* __restrict__ in, unsigned short* __restrict__ out,
                                 int n4) {
    int i = blockIdx.x * TPB + threadIdx.x;
    if (i < n4) {
        float4 v = ((const float4*)in)[i];
        ushort4 o;
        o.x = f2bf(v.x); o.y = f2bf(v.y); o.z = f2bf(v.z); o.w = f2bf(v.w);
        ((ushort4*)out)[i] = o;
    }
}

// ---------- weight prep: cast + transpose to [CO][K] bf16 ----------
__global__ void weight_prep_kernel(const float* __restrict__ Wl1, const float* __restrict__ Wr1,
                                   const float* __restrict__ Wl2, const float* __restrict__ Wr2,
                                   unsigned short* __restrict__ Wt1,
                                   unsigned short* __restrict__ Wt2a,
                                   unsigned short* __restrict__ Wt2b) {
    int idx = blockIdx.x * TPB + threadIdx.x;
    if (idx < 128 * 256) {
        int co = idx & 127, k = idx >> 7;
        float v = (k < 128) ? Wl1[k * 128 + co] : Wr1[(k - 128) * 128 + co];
        Wt1[(size_t)co * 256 + k] = f2bf(v);
    } else if (idx < 128 * 256 + 64 * 128) {
        int j = idx - 128 * 256;
        int co = j & 63, k = j >> 6;
        Wt2a[(size_t)co * 128 + k] = f2bf(Wl2[k * 64 + co]);
    } else if (idx < 128 * 256 + 2 * 64 * 128) {
        int j = idx - 128 * 256 - 64 * 128;
        int co = j & 63, k = j >> 6;
        Wt2b[(size_t)co * 128 + k] = f2bf(Wr2[k * 64 + co]);
    }
}

// ---------- gather-mean over slack buckets, degree-banded ----------
// Node order comes from pnode (degree-sorted within each bin; -1 = pad).
// LPN = D/8 lanes per node (16B loads). Ids 0..31 preloaded (coalesced) and
// distributed via __shfl; 4-deep main loop + one masked-fma tail step
// (clamped addresses, 0/1 weights) replaces the serial remainder.
template <int D, bool FINALADD>
__global__ __launch_bounds__(256) void gather_mean_kernel(
    const unsigned short* __restrict__ feat,  // [N,D] bf16
    const int* __restrict__ nbrp,             // [N,CAP] src ids
    const int* __restrict__ cursor,           // [N] true degree
    const int* __restrict__ pnode,            // [nslot] degree-banded node order
    const float* __restrict__ ub,             // [N,D] f32 (FINALADD only)
    void* __restrict__ outv,                  // [N,D] bf16 or f32
    int nslot) {
    constexpr int LPN = D / 8;          // 16 (D=128) or 8 (D=64)
    int gid = blockIdx.x * TPB + threadIdx.x;
    int slot = gid / LPN;
    if (slot >= nslot) return;
    int node = pnode[slot];
    if (node < 0) return;
    const int lane = threadIdx.x & 63;
    const int part = lane & (LPN - 1);
    const int base = lane & ~(LPN - 1);
    const unsigned short* fcol = feat + part * 8;

    const int* lst = nbrp + (size_t)node * CAP;
    int dtrue = cursor[node];
    int d = min(dtrue, CAP);
    int d32 = min(d, 32);

    // preload ids 0..31 for this node's group (coalesced 4B loads)
    int id0 = lst[part];
    int id1 = lst[LPN + part];
    int id2 = 0, id3 = 0;
    if (LPN == 8) {
        id2 = lst[2 * LPN + part];
        id3 = lst[3 * LPN + part];
    }

    float a0[8], a1[8], a2[8], a3[8];
#pragma unroll
    for (int i = 0; i < 8; i++) { a0[i] = 0.f; a1[i] = 0.f; a2[i] = 0.f; a3[i] = 0.f; }

    int j = 0;
    int full = d32 & ~3;
    for (; j < full; j += 4) {
        int blk = (LPN == 8) ? (j >> 3) : (j >> 4);
        int sel = (blk == 0) ? id0 : (blk == 1) ? id1 : (blk == 2) ? id2 : id3;
        int sl = base + (j & (LPN - 1));
        int s0 = __shfl(sel, sl + 0);
        int s1 = __shfl(sel, sl + 1);
        int s2 = __shfl(sel, sl + 2);
        int s3 = __shfl(sel, sl + 3);
        bf16x8 v0 = *(const bf16x8*)(fcol + (size_t)s0 * D);
        bf16x8 v1 = *(const bf16x8*)(fcol + (size_t)s1 * D);
        bf16x8 v2 = *(const bf16x8*)(fcol + (size_t)s2 * D);
        bf16x8 v3 = *(const bf16x8*)(fcol + (size_t)s3 * D);
#pragma unroll
        for (int i = 0; i < 8; i++) {
            a0[i] += bfe2f(v0[i]);
            a1[i] += bfe2f(v1[i]);
            a2[i] += bfe2f(v2[i]);
            a3[i] += bfe2f(v3[i]);
        }
    }
    if (j < d32) {
        // masked tail: 1-3 valid neighbors; clamp addresses, weight 0/1
        int blk = (LPN == 8) ? (j >> 3) : (j >> 4);
        int sel = (blk == 0) ? id0 : (blk == 1) ? id1 : (blk == 2) ? id2 : id3;
        int sl = base + (j & (LPN - 1));
        int s0 = __shfl(sel, sl + 0);   // slot j valid by loop condition
        int s1 = __shfl(sel, sl + 1);
        int s2 = __shfl(sel, sl + 2);
        bool m1 = (j + 1 < d32), m2 = (j + 2 < d32);
        s1 = m1 ? s1 : s0;
        s2 = m2 ? s2 : s0;
        float f1 = m1 ? 1.f : 0.f, f2 = m2 ? 1.f : 0.f;
        bf16x8 v0 = *(const bf16x8*)(fcol + (size_t)s0 * D);
        bf16x8 v1 = *(const bf16x8*)(fcol + (size_t)s1 * D);
        bf16x8 v2 = *(const bf16x8*)(fcol + (size_t)s2 * D);
#pragma unroll
        for (int i = 0; i < 8; i++) {
            a0[i] += bfe2f(v0[i]);
            a1[i] = fmaf(f1, bfe2f(v1[i]), a1[i]);
            a2[i] = fmaf(f2, bfe2f(v2[i]), a2[i]);
        }
        j = d32;
    }
    // rare spill: d > 32
    for (; j < d; j++) {
        int s0 = lst[j];
        bf16x8 v0 = *(const bf16x8*)(fcol + (size_t)s0 * D);
#pragma unroll
        for (int i = 0; i < 8; i++) a0[i] += bfe2f(v0[i]);
    }

    float sc = 1.0f / (float)max(dtrue, 1);
    float r[8];
#pragma unroll
    for (int i = 0; i < 8; i++) r[i] = (a0[i] + a1[i] + a2[i] + a3[i]) * sc;

    if (FINALADD) {
        const float* up = ub + (size_t)node * D + part * 8;
        float* op = (float*)outv + (size_t)node * D + part * 8;
        float4 u0 = *(const float4*)(up);
        float4 u1 = *(const float4*)(up + 4);
        float4 o0 = make_float4(r[0] + u0.x, r[1] + u0.y, r[2] + u0.z, r[3] + u0.w);
        float4 o1 = make_float4(r[4] + u1.x, r[5] + u1.y, r[6] + u1.z, r[7] + u1.w);
        *(float4*)(op) = o0;
        *(float4*)(op + 4) = o1;
    } else {
        bf16x8 st;
#pragma unroll
        for (int i = 0; i < 8; i++) st[i] = (short)f2bf(r[i]);
        *(bf16x8*)((unsigned short*)outv + (size_t)node * D + part * 8) = st;
    }
}

// ---------- MFMA GEMM, B-panel resident in registers (layer 1) ----------
__global__ __launch_bounds__(256) void sage1_mfma_kernel(
    const unsigned short* __restrict__ A1,    // aggb [N,128]
    const unsigned short* __restrict__ A2,    // xb   [N,128]
    const unsigned short* __restrict__ Wt,    // [128][256] bf16
    const float* __restrict__ bias,           // [128]
    unsigned short* __restrict__ outb,        // [N,128] bf16
    int N, int ntiles) {
    constexpr int K = 256, KS = 8;

    const int tid = threadIdx.x;
    const int lane = tid & 63;
    const int wave = tid >> 6;
    const int lrow = lane & 15;
    const int kb = (lane >> 4) * 8;
    const int colgrp = wave & 1;
    const int mslot = wave >> 1;
    const int colbase = colgrp * 64;

    bf16x8 B[4][KS];
#pragma unroll
    for (int t = 0; t < 4; t++)
#pragma unroll
        for (int ks = 0; ks < KS; ks++)
            B[t][ks] = *(const bf16x8*)(Wt + (size_t)(colbase + t * 16 + lrow) * K + ks * 32 + kb);

    for (int tile = blockIdx.x * 2 + mslot; tile < ntiles; tile += gridDim.x * 2) {
        const int m0 = tile * 16;
        const int arow = min(m0 + lrow, N - 1);

        bf16x8 a[KS];
#pragma unroll
        for (int ks = 0; ks < KS; ks++) {
            if (ks >= 4)
                a[ks] = *(const bf16x8*)(A2 + (size_t)arow * 128 + (ks - 4) * 32 + kb);
            else
                a[ks] = *(const bf16x8*)(A1 + (size_t)arow * 128 + ks * 32 + kb);
        }

        f32x4 acc[4];
#pragma unroll
        for (int t = 0; t < 4; t++) acc[t] = (f32x4){0.f, 0.f, 0.f, 0.f};
#pragma unroll
        for (int ks = 0; ks < KS; ks++)
#pragma unroll
            for (int t = 0; t < 4; t++)
                acc[t] = __builtin_amdgcn_mfma_f32_16x16x32_bf16(a[ks], B[t][ks], acc[t], 0, 0, 0);

        const int mb = m0 + (lane >> 4) * 4;
#pragma unroll
        for (int t = 0; t < 4; t++) {
            const int col = colbase + t * 16 + lrow;
            const float bv = bias[col];
#pragma unroll
            for (int r = 0; r < 4; r++) {
                const int m = mb + r;
                if (m < N) {
                    float v = fmaxf(acc[t][r] + bv, 0.f);
                    outb[(size_t)m * 128 + col] = f2bf(v);
                }
            }
        }
    }
}

// ---------- dual-output layer-2 GEMM ----------
__global__ __launch_bounds__(256) void gemm64_dual_kernel(
    const unsigned short* __restrict__ h,     // [N,128] bf16
    const unsigned short* __restrict__ Wta,   // [64][128] bf16 (Wl2^T)
    const unsigned short* __restrict__ Wtb,   // [64][128] bf16 (Wr2^T)
    const float* __restrict__ bias,           // [64]
    unsigned short* __restrict__ tb,          // [N,64] bf16
    float* __restrict__ ub,                   // [N,64] f32
    int N, int ntiles) {
    constexpr int K = 128, KS = 4;

    const int tid = threadIdx.x;
    const int lane = tid & 63;
    const int wave = tid >> 6;
    const int lrow = lane & 15;
    const int kb = (lane >> 4) * 8;

    bf16x8 Ba[4][KS], Bb[4][KS];
#pragma unroll
    for (int t = 0; t < 4; t++)
#pragma unroll
        for (int ks = 0; ks < KS; ks++) {
            Ba[t][ks] = *(const bf16x8*)(Wta + (size_t)(t * 16 + lrow) * K + ks * 32 + kb);
            Bb[t][ks] = *(const bf16x8*)(Wtb + (size_t)(t * 16 + lrow) * K + ks * 32 + kb);
        }

    for (int tile = blockIdx.x * 4 + wave; tile < ntiles; tile += gridDim.x * 4) {
        const int m0 = tile * 16;
        const int arow = min(m0 + lrow, N - 1);

        bf16x8 a[KS];
#pragma unroll
        for (int ks = 0; ks < KS; ks++)
            a[ks] = *(const bf16x8*)(h + (size_t)arow * 128 + ks * 32 + kb);

        f32x4 acct[4], accu[4];
#pragma unroll
        for (int t = 0; t < 4; t++) {
            acct[t] = (f32x4){0.f, 0.f, 0.f, 0.f};
            accu[t] = (f32x4){0.f, 0.f, 0.f, 0.f};
        }
#pragma unroll
        for (int ks = 0; ks < KS; ks++)
#pragma unroll
            for (int t = 0; t < 4; t++) {
                acct[t] = __builtin_amdgcn_mfma_f32_16x16x32_bf16(a[ks], Ba[t][ks], acct[t], 0, 0, 0);
                accu[t] = __builtin_amdgcn_mfma_f32_16x16x32_bf16(a[ks], Bb[t][ks], accu[t], 0, 0, 0);
            }

        const int mb = m0 + (lane >> 4) * 4;
#pragma unroll
        for (int t = 0; t < 4; t++) {
            const int col = t * 16 + lrow;
            const float bv = bias[col];
#pragma unroll
            for (int r = 0; r < 4; r++) {
                const int m = mb + r;
                if (m < N) {
                    tb[(size_t)m * 64 + col] = f2bf(acct[t][r]);
                    ub[(size_t)m * 64 + col] = accu[t][r] + bv;
                }
            }
        }
    }
}

extern "C" void kernel_launch(void* const* d_in, const int* in_sizes, int n_in,
                              void* d_out, int out_size, void* d_ws, size_t ws_size,
                              hipStream_t stream) {
    const float* x   = (const float*)d_in[0];
    const int* ei    = (const int*)d_in[1];
    const float* Wl1 = (const float*)d_in[2];
    const float* Wr1 = (const float*)d_in[3];
    const float* b1  = (const float*)d_in[4];
    const float* Wl2 = (const float*)d_in[5];
    const float* Wr2 = (const float*)d_in[6];
    const float* b2  = (const float*)d_in[7];
    float* out = (float*)d_out;

    const int N = in_sizes[0] / 128;
    const int E = in_sizes[1] / 2;
    const int* src = ei;
    const int* dst = ei + E;

    const int epb = (E + NBLKA - 1) / NBLKA;
    const int ntiles = (N + 15) / 16;
    const int nNodeBins = (N + 511) >> 9;
    const int nslot = nNodeBins << 9;

    // d_out (N*64 f32 = N*128 bf16, 25.6 MB) doubles as scratch:
    //   phase 1: xb (bf16 [N,128])   — dead after sage1
    //   phase 2: ub (f32  [N,64])    — written by gemm_dual, consumed+overwritten
    //                                   in-place by the final gather.
    unsigned short* xb = (unsigned short*)d_out;
    float* ub          = (float*)d_out;

    // workspace: [h: N*128 bf16][aggb: N*128 bf16 | sorted: E int2 overlay]
    //            [tb: N*64 bf16][Wt1 128*256][Wt2a 64*128][Wt2b 64*128]
    //            [cursor: N][nbrp: N*CAP][blockhist: NBIN*NBLKA]
    //            [bintotal: NBIN][binstart: NBIN+1][boff: NBIN*NBLKA][pnode: nslot]
    unsigned short* h    = (unsigned short*)d_ws;
    unsigned short* aggb = h + (size_t)N * 128;
    int2* sorted         = (int2*)aggb;          // overlay: sorted dead before aggb written
    unsigned short* tb   = aggb + (size_t)N * 128;
    unsigned short* Wt1  = tb + (size_t)N * 64;
    unsigned short* Wt2a = Wt1 + 128 * 256;
    unsigned short* Wt2b = Wt2a + 64 * 128;
    int* cursor    = (int*)(Wt2b + 64 * 128);
    int* nbrp      = cursor + N;
    int* blockhist = nbrp + (size_t)N * CAP;
    int* bintotal  = blockhist + NBIN * NBLKA;
    int* binstart  = bintotal + NBIN;
    int* boff      = binstart + (NBIN + 1);
    int* pnode     = boff + NBIN * NBLKA;

    // ---- weight prep + binned-sort CSR build ----
    weight_prep_kernel<<<(128 * 256 + 2 * 64 * 128 + TPB - 1) / TPB, TPB, 0, stream>>>(
        Wl1, Wr1, Wl2, Wr2, Wt1, Wt2a, Wt2b);
    binA_count<<<NBLKA, TPB, 0, stream>>>(dst, blockhist, E, epb);
    binA_total<<<NBIN, TPB, 0, stream>>>(blockhist, bintotal);
    binA_scan<<<1, NBIN, 0, stream>>>(bintotal, binstart);
    binA_boff<<<NBIN, NBLKA, 0, stream>>>(blockhist, binstart, boff);
    binA_scatter<<<NBLKA, TPB, 0, stream>>>(src, dst, boff, sorted, E, epb);
    binB_build<<<nNodeBins, TPB, 0, stream>>>(sorted, binstart, cursor, nbrp, pnode, N);

    // ---- layer 1 ----
    cast_bf16_kernel<<<((N * 128 / 4) + TPB - 1) / TPB, TPB, 0, stream>>>(x, xb, N * 128 / 4);
    gather_mean_kernel<128, false><<<(nslot * 16 + TPB - 1) / TPB, TPB, 0, stream>>>(
        xb, nbrp, cursor, pnode, nullptr, aggb, nslot);
    sage1_mfma_kernel<<<512, 256, 0, stream>>>(aggb, xb, Wt1, b1, h, N, ntiles);
    // xb dead from here; ub overlays it (same d_out region).

    // ---- layer 2 ----
    gemm64_dual_kernel<<<512, 256, 0, stream>>>(h, Wt2a, Wt2b, b2, tb, ub, N, ntiles);
    gather_mean_kernel<64, true><<<(nslot * 8 + TPB - 1) / TPB, TPB, 0, stream>>>(
        tb, nbrp, cursor, pnode, ub, out, nslot);
}

// Round 11
// 200.772 us; speedup vs baseline: 1.0619x; 1.0619x over previous
//
#include <hip/hip_runtime.h>

// GraphSAGE 2-layer encoder: binned-sort slack-bucket CSR (LDS atomics only),
// bf16 activations, register-resident-B MFMA GEMMs, dual-output layer-2 GEMM,
// gathers with FIXED-32 masked unrolled trip (deep load pipelining, no
// data-dependent branches). d_out doubles as scratch (xb/ub).
// N=100000, E=1600000, D_IN=128, D_HID=128, D_OUT=64.

constexpr int TPB = 256;
constexpr int CAP = 64;    // neighbor slots per node; P(Poisson(16) >= 64) ~ 1e-20
constexpr int NBIN = 256;  // dst bins of 512 nodes (dst>>9)
constexpr int NBLKA = 512; // phase-A blocks

typedef __attribute__((ext_vector_type(8))) short bf16x8;
typedef __attribute__((ext_vector_type(4))) float f32x4;

// ---------- bf16 helpers ----------
static __device__ __forceinline__ unsigned short f2bf(float f) {
    unsigned int u = __float_as_uint(f);
    u += 0x7fffu + ((u >> 16) & 1u);   // round-to-nearest-even
    return (unsigned short)(u >> 16);
}
static __device__ __forceinline__ float bfe2f(short s) {
    return __uint_as_float(((unsigned int)(unsigned short)s) << 16);
}

// ================= binned counting sort (no global atomics) =================

__global__ void binA_count(const int* __restrict__ dst, int* __restrict__ blockhist,
                           int E, int epb) {
    __shared__ int hist[NBIN];
    hist[threadIdx.x] = 0;
    __syncthreads();
    int e0 = blockIdx.x * epb, e1 = min(E, e0 + epb);
    for (int i = e0 + threadIdx.x; i < e1; i += TPB)
        atomicAdd(&hist[dst[i] >> 9], 1);
    __syncthreads();
    blockhist[threadIdx.x * NBLKA + blockIdx.x] = hist[threadIdx.x];
}

__global__ void binA_total(const int* __restrict__ blockhist, int* __restrict__ bintotal) {
    __shared__ int s[TPB];
    int b = blockIdx.x;
    int sum = 0;
    for (int i = threadIdx.x; i < NBLKA; i += TPB) sum += blockhist[b * NBLKA + i];
    s[threadIdx.x] = sum;
    __syncthreads();
    for (int o = 128; o > 0; o >>= 1) {
        if (threadIdx.x < o) s[threadIdx.x] += s[threadIdx.x + o];
        __syncthreads();
    }
    if (threadIdx.x == 0) bintotal[b] = s[0];
}

__global__ void binA_scan(const int* __restrict__ bintotal, int* __restrict__ binstart) {
    __shared__ int s[NBIN];
    int t = threadIdx.x;
    s[t] = bintotal[t];
    __syncthreads();
    for (int o = 1; o < NBIN; o <<= 1) {
        int v = (t >= o) ? s[t - o] : 0;
        __syncthreads();
        s[t] += v;
        __syncthreads();
    }
    binstart[t] = t ? s[t - 1] : 0;
    if (t == NBIN - 1) binstart[NBIN] = s[NBIN - 1];
}

__global__ void binA_boff(const int* __restrict__ blockhist, const int* __restrict__ binstart,
                          int* __restrict__ boff) {
    __shared__ int s[NBLKA];
    int b = blockIdx.x, t = threadIdx.x;
    s[t] = blockhist[b * NBLKA + t];
    __syncthreads();
    for (int o = 1; o < NBLKA; o <<= 1) {
        int v = (t >= o) ? s[t - o] : 0;
        __syncthreads();
        s[t] += v;
        __syncthreads();
    }
    int excl = t ? s[t - 1] : 0;
    boff[b * NBLKA + t] = binstart[b] + excl;
}

__global__ void binA_scatter(const int* __restrict__ src, const int* __restrict__ dst,
                             const int* __restrict__ boff, int2* __restrict__ sorted,
                             int E, int epb) {
    __shared__ int base[NBIN];
    __shared__ int lcur[NBIN];
    int t = threadIdx.x, blk = blockIdx.x;
    base[t] = boff[t * NBLKA + blk];
    lcur[t] = 0;
    __syncthreads();
    int e0 = blk * epb, e1 = min(E, e0 + epb);
    for (int i = e0 + t; i < e1; i += TPB) {
        int d = dst[i];
        int b = d >> 9;
        int p = base[b] + atomicAdd(&lcur[b], 1);
        sorted[p] = make_int2(src[i], d);
    }
}

// B: one block per 512-node bin; LDS cursors; XCD-local nbrp writes.
__global__ void binB_build(const int2* __restrict__ sorted, const int* __restrict__ binstart,
                           int* __restrict__ cursor, int* __restrict__ nbrp, int N) {
    __shared__ int lcur[512];
    int t = threadIdx.x, b = blockIdx.x;
    lcur[t] = 0;
    lcur[t + 256] = 0;
    __syncthreads();
    int lo = binstart[b], hi = binstart[b + 1];
    int node0 = b << 9;
    for (int i = lo + t; i < hi; i += TPB) {
        int2 e = sorted[i];
        int p = atomicAdd(&lcur[e.y - node0], 1);
        if (p < CAP) nbrp[(size_t)e.y * CAP + p] = e.x;
    }
    __syncthreads();
    for (int k = t; k < 512; k += TPB) {
        int node = node0 + k;
        if (node < N) cursor[node] = lcur[k];
    }
}

// ---------- fp32 -> bf16 cast ----------
__global__ void cast_bf16_kernel(const float* __restrict__ in, unsigned short* __restrict__ out,
                                 int n4) {
    int i = blockIdx.x * TPB + threadIdx.x;
    if (i < n4) {
        float4 v = ((const float4*)in)[i];
        ushort4 o;
        o.x = f2bf(v.x); o.y = f2bf(v.y); o.z = f2bf(v.z); o.w = f2bf(v.w);
        ((ushort4*)out)[i] = o;
    }
}

// ---------- weight prep: cast + transpose to [CO][K] bf16 ----------
__global__ void weight_prep_kernel(const float* __restrict__ Wl1, const float* __restrict__ Wr1,
                                   const float* __restrict__ Wl2, const float* __restrict__ Wr2,
                                   unsigned short* __restrict__ Wt1,
                                   unsigned short* __restrict__ Wt2a,
                                   unsigned short* __restrict__ Wt2b) {
    int idx = blockIdx.x * TPB + threadIdx.x;
    if (idx < 128 * 256) {
        int co = idx & 127, k = idx >> 7;
        float v = (k < 128) ? Wl1[k * 128 + co] : Wr1[(k - 128) * 128 + co];
        Wt1[(size_t)co * 256 + k] = f2bf(v);
    } else if (idx < 128 * 256 + 64 * 128) {
        int j = idx - 128 * 256;
        int co = j & 63, k = j >> 6;
        Wt2a[(size_t)co * 128 + k] = f2bf(Wl2[k * 64 + co]);
    } else if (idx < 128 * 256 + 2 * 64 * 128) {
        int j = idx - 128 * 256 - 64 * 128;
        int co = j & 63, k = j >> 6;
        Wt2b[(size_t)co * 128 + k] = f2bf(Wr2[k * 64 + co]);
    }
}

// ---------- gather-mean, fixed-32 masked unrolled trip ----------
// LPN = D/8 lanes per node (16B loads). Ids 0..31 preloaded coalesced and
// distributed via __shfl. Every node processes exactly 32 slots (fully
// unrolled, no data-dependent branches): slot j gets weight (j<d)?1:0 and
// address clamped to row 0 when invalid (row 0 is L1-resident -> free).
// The straight-line body lets the compiler pipeline loads many slots deep.
// d>32 spill handled by a rare scalar loop. Natural node order (coalesced
// preloads and output writes).
template <int D, bool FINALADD>
__global__ __launch_bounds__(256) void gather_mean_kernel(
    const unsigned short* __restrict__ feat,  // [N,D] bf16
    const int* __restrict__ nbrp,             // [N,CAP] src ids
    const int* __restrict__ cursor,           // [N] true degree
    const float* __restrict__ ub,             // [N,D] f32 (FINALADD only)
    void* __restrict__ outv,                  // [N,D] bf16 or f32
    int N) {
    constexpr int LPN = D / 8;          // 16 (D=128) or 8 (D=64)
    int gid = blockIdx.x * TPB + threadIdx.x;
    int node = gid / LPN;
    if (node >= N) return;
    const int lane = threadIdx.x & 63;
    const int part = lane & (LPN - 1);
    const int base = lane & ~(LPN - 1);
    const unsigned short* fcol = feat + part * 8;

    const int* lst = nbrp + (size_t)node * CAP;
    int dtrue = cursor[node];
    int d = min(dtrue, CAP);

    // preload ids 0..31 for this node's group (coalesced 4B loads)
    int id0 = lst[part];
    int id1 = lst[LPN + part];
    int id2 = 0, id3 = 0;
    if (LPN == 8) {
        id2 = lst[2 * LPN + part];
        id3 = lst[3 * LPN + part];
    }

    float a0[8], a1[8], a2[8], a3[8];
#pragma unroll
    for (int i = 0; i < 8; i++) { a0[i] = 0.f; a1[i] = 0.f; a2[i] = 0.f; a3[i] = 0.f; }

#pragma unroll
    for (int c = 0; c < 8; c++) {
        const int j = c * 4;
        const int blk = (LPN == 8) ? (j >> 3) : (j >> 4);
        int sel = (blk == 0) ? id0 : (blk == 1) ? id1 : (blk == 2) ? id2 : id3;
        const int sl = base + (j & (LPN - 1));
        int s0 = __shfl(sel, sl + 0);
        int s1 = __shfl(sel, sl + 1);
        int s2 = __shfl(sel, sl + 2);
        int s3 = __shfl(sel, sl + 3);
        float w0 = (j + 0 < d) ? 1.f : 0.f;
        float w1 = (j + 1 < d) ? 1.f : 0.f;
        float w2 = (j + 2 < d) ? 1.f : 0.f;
        float w3 = (j + 3 < d) ? 1.f : 0.f;
        s0 = (j + 0 < d) ? s0 : 0;
        s1 = (j + 1 < d) ? s1 : 0;
        s2 = (j + 2 < d) ? s2 : 0;
        s3 = (j + 3 < d) ? s3 : 0;
        bf16x8 v0 = *(const bf16x8*)(fcol + (size_t)s0 * D);
        bf16x8 v1 = *(const bf16x8*)(fcol + (size_t)s1 * D);
        bf16x8 v2 = *(const bf16x8*)(fcol + (size_t)s2 * D);
        bf16x8 v3 = *(const bf16x8*)(fcol + (size_t)s3 * D);
#pragma unroll
        for (int i = 0; i < 8; i++) {
            a0[i] = fmaf(w0, bfe2f(v0[i]), a0[i]);
            a1[i] = fmaf(w1, bfe2f(v1[i]), a1[i]);
            a2[i] = fmaf(w2, bfe2f(v2[i]), a2[i]);
            a3[i] = fmaf(w3, bfe2f(v3[i]), a3[i]);
        }
    }
    // rare spill: d > 32
    for (int j = 32; j < d; j++) {
        int s0 = lst[j];
        bf16x8 v0 = *(const bf16x8*)(fcol + (size_t)s0 * D);
#pragma unroll
        for (int i = 0; i < 8; i++) a0[i] += bfe2f(v0[i]);
    }

    float sc = 1.0f / (float)max(dtrue, 1);
    float r[8];
#pragma unroll
    for (int i = 0; i < 8; i++) r[i] = (a0[i] + a1[i] + a2[i] + a3[i]) * sc;

    if (FINALADD) {
        const float* up = ub + (size_t)node * D + part * 8;
        float* op = (float*)outv + (size_t)node * D + part * 8;
        float4 u0 = *(const float4*)(up);
        float4 u1 = *(const float4*)(up + 4);
        float4 o0 = make_float4(r[0] + u0.x, r[1] + u0.y, r[2] + u0.z, r[3] + u0.w);
        float4 o1 = make_float4(r[4] + u1.x, r[5] + u1.y, r[6] + u1.z, r[7] + u1.w);
        *(float4*)(op) = o0;
        *(float4*)(op + 4) = o1;
    } else {
        bf16x8 st;
#pragma unroll
        for (int i = 0; i < 8; i++) st[i] = (short)f2bf(r[i]);
        *(bf16x8*)((unsigned short*)outv + (size_t)node * D + part * 8) = st;
    }
}

// ---------- MFMA GEMM, B-panel resident in registers (layer 1) ----------
__global__ __launch_bounds__(256) void sage1_mfma_kernel(
    const unsigned short* __restrict__ A1,    // aggb [N,128]
    const unsigned short* __restrict__ A2,    // xb   [N,128]
    const unsigned short* __restrict__ Wt,    // [128][256] bf16
    const float* __restrict__ bias,           // [128]
    unsigned short* __restrict__ outb,        // [N,128] bf16
    int N, int ntiles) {
    constexpr int K = 256, KS = 8;

    const int tid = threadIdx.x;
    const int lane = tid & 63;
    const int wave = tid >> 6;
    const int lrow = lane & 15;
    const int kb = (lane >> 4) * 8;
    const int colgrp = wave & 1;
    const int mslot = wave >> 1;
    const int colbase = colgrp * 64;

    bf16x8 B[4][KS];
#pragma unroll
    for (int t = 0; t < 4; t++)
#pragma unroll
        for (int ks = 0; ks < KS; ks++)
            B[t][ks] = *(const bf16x8*)(Wt + (size_t)(colbase + t * 16 + lrow) * K + ks * 32 + kb);

    for (int tile = blockIdx.x * 2 + mslot; tile < ntiles; tile += gridDim.x * 2) {
        const int m0 = tile * 16;
        const int arow = min(m0 + lrow, N - 1);

        bf16x8 a[KS];
#pragma unroll
        for (int ks = 0; ks < KS; ks++) {
            if (ks >= 4)
                a[ks] = *(const bf16x8*)(A2 + (size_t)arow * 128 + (ks - 4) * 32 + kb);
            else
                a[ks] = *(const bf16x8*)(A1 + (size_t)arow * 128 + ks * 32 + kb);
        }

        f32x4 acc[4];
#pragma unroll
        for (int t = 0; t < 4; t++) acc[t] = (f32x4){0.f, 0.f, 0.f, 0.f};
#pragma unroll
        for (int ks = 0; ks < KS; ks++)
#pragma unroll
            for (int t = 0; t < 4; t++)
                acc[t] = __builtin_amdgcn_mfma_f32_16x16x32_bf16(a[ks], B[t][ks], acc[t], 0, 0, 0);

        const int mb = m0 + (lane >> 4) * 4;
#pragma unroll
        for (int t = 0; t < 4; t++) {
            const int col = colbase + t * 16 + lrow;
            const float bv = bias[col];
#pragma unroll
            for (int r = 0; r < 4; r++) {
                const int m = mb + r;
                if (m < N) {
                    float v = fmaxf(acc[t][r] + bv, 0.f);
                    outb[(size_t)m * 128 + col] = f2bf(v);
                }
            }
        }
    }
}

// ---------- dual-output layer-2 GEMM ----------
__global__ __launch_bounds__(256) void gemm64_dual_kernel(
    const unsigned short* __restrict__ h,     // [N,128] bf16
    const unsigned short* __restrict__ Wta,   // [64][128] bf16 (Wl2^T)
    const unsigned short* __restrict__ Wtb,   // [64][128] bf16 (Wr2^T)
    const float* __restrict__ bias,           // [64]
    unsigned short* __restrict__ tb,          // [N,64] bf16
    float* __restrict__ ub,                   // [N,64] f32
    int N, int ntiles) {
    constexpr int K = 128, KS = 4;

    const int tid = threadIdx.x;
    const int lane = tid & 63;
    const int wave = tid >> 6;
    const int lrow = lane & 15;
    const int kb = (lane >> 4) * 8;

    bf16x8 Ba[4][KS], Bb[4][KS];
#pragma unroll
    for (int t = 0; t < 4; t++)
#pragma unroll
        for (int ks = 0; ks < KS; ks++) {
            Ba[t][ks] = *(const bf16x8*)(Wta + (size_t)(t * 16 + lrow) * K + ks * 32 + kb);
            Bb[t][ks] = *(const bf16x8*)(Wtb + (size_t)(t * 16 + lrow) * K + ks * 32 + kb);
        }

    for (int tile = blockIdx.x * 4 + wave; tile < ntiles; tile += gridDim.x * 4) {
        const int m0 = tile * 16;
        const int arow = min(m0 + lrow, N - 1);

        bf16x8 a[KS];
#pragma unroll
        for (int ks = 0; ks < KS; ks++)
            a[ks] = *(const bf16x8*)(h + (size_t)arow * 128 + ks * 32 + kb);

        f32x4 acct[4], accu[4];
#pragma unroll
        for (int t = 0; t < 4; t++) {
            acct[t] = (f32x4){0.f, 0.f, 0.f, 0.f};
            accu[t] = (f32x4){0.f, 0.f, 0.f, 0.f};
        }
#pragma unroll
        for (int ks = 0; ks < KS; ks++)
#pragma unroll
            for (int t = 0; t < 4; t++) {
                acct[t] = __builtin_amdgcn_mfma_f32_16x16x32_bf16(a[ks], Ba[t][ks], acct[t], 0, 0, 0);
                accu[t] = __builtin_amdgcn_mfma_f32_16x16x32_bf16(a[ks], Bb[t][ks], accu[t], 0, 0, 0);
            }

        const int mb = m0 + (lane >> 4) * 4;
#pragma unroll
        for (int t = 0; t < 4; t++) {
            const int col = t * 16 + lrow;
            const float bv = bias[col];
#pragma unroll
            for (int r = 0; r < 4; r++) {
                const int m = mb + r;
                if (m < N) {
                    tb[(size_t)m * 64 + col] = f2bf(acct[t][r]);
                    ub[(size_t)m * 64 + col] = accu[t][r] + bv;
                }
            }
        }
    }
}

extern "C" void kernel_launch(void* const* d_in, const int* in_sizes, int n_in,
                              void* d_out, int out_size, void* d_ws, size_t ws_size,
                              hipStream_t stream) {
    const float* x   = (const float*)d_in[0];
    const int* ei    = (const int*)d_in[1];
    const float* Wl1 = (const float*)d_in[2];
    const float* Wr1 = (const float*)d_in[3];
    const float* b1  = (const float*)d_in[4];
    const float* Wl2 = (const float*)d_in[5];
    const float* Wr2 = (const float*)d_in[6];
    const float* b2  = (const float*)d_in[7];
    float* out = (float*)d_out;

    const int N = in_sizes[0] / 128;
    const int E = in_sizes[1] / 2;
    const int* src = ei;
    const int* dst = ei + E;

    const int epb = (E + NBLKA - 1) / NBLKA;
    const int ntiles = (N + 15) / 16;
    const int nNodeBins = (N + 511) >> 9;

    // d_out (N*64 f32 = N*128 bf16, 25.6 MB) doubles as scratch:
    //   phase 1: xb (bf16 [N,128])   — dead after sage1
    //   phase 2: ub (f32  [N,64])    — written by gemm_dual, consumed+overwritten
    //                                   in-place by the final gather.
    unsigned short* xb = (unsigned short*)d_out;
    float* ub          = (float*)d_out;

    // workspace: [h: N*128 bf16][aggb: N*128 bf16 | sorted: E int2 overlay]
    //            [tb: N*64 bf16][Wt1 128*256][Wt2a 64*128][Wt2b 64*128]
    //            [cursor: N][nbrp: N*CAP][blockhist: NBIN*NBLKA]
    //            [bintotal: NBIN][binstart: NBIN+1][boff: NBIN*NBLKA]
    unsigned short* h    = (unsigned short*)d_ws;
    unsigned short* aggb = h + (size_t)N * 128;
    int2* sorted         = (int2*)aggb;          // overlay: sorted dead before aggb written
    unsigned short* tb   = aggb + (size_t)N * 128;
    unsigned short* Wt1  = tb + (size_t)N * 64;
    unsigned short* Wt2a = Wt1 + 128 * 256;
    unsigned short* Wt2b = Wt2a + 64 * 128;
    int* cursor    = (int*)(Wt2b + 64 * 128);
    int* nbrp      = cursor + N;
    int* blockhist = nbrp + (size_t)N * CAP;
    int* bintotal  = blockhist + NBIN * NBLKA;
    int* binstart  = bintotal + NBIN;
    int* boff      = binstart + (NBIN + 1);

    // ---- weight prep + binned-sort CSR build ----
    weight_prep_kernel<<<(128 * 256 + 2 * 64 * 128 + TPB - 1) / TPB, TPB, 0, stream>>>(
        Wl1, Wr1, Wl2, Wr2, Wt1, Wt2a, Wt2b);
    binA_count<<<NBLKA, TPB, 0, stream>>>(dst, blockhist, E, epb);
    binA_total<<<NBIN, TPB, 0, stream>>>(blockhist, bintotal);
    binA_scan<<<1, NBIN, 0, stream>>>(bintotal, binstart);
    binA_boff<<<NBIN, NBLKA, 0, stream>>>(blockhist, binstart, boff);
    binA_scatter<<<NBLKA, TPB, 0, stream>>>(src, dst, boff, sorted, E, epb);
    binB_build<<<nNodeBins, TPB, 0, stream>>>(sorted, binstart, cursor, nbrp, N);

    // ---- layer 1 ----
    cast_bf16_kernel<<<((N * 128 / 4) + TPB - 1) / TPB, TPB, 0, stream>>>(x, xb, N * 128 / 4);
    gather_mean_kernel<128, false><<<(N * 16 + TPB - 1) / TPB, TPB, 0, stream>>>(
        xb, nbrp, cursor, nullptr, aggb, N);
    sage1_mfma_kernel<<<512, 256, 0, stream>>>(aggb, xb, Wt1, b1, h, N, ntiles);
    // xb dead from here; ub overlays it (same d_out region).

    // ---- layer 2 ----
    gemm64_dual_kernel<<<512, 256, 0, stream>>>(h, Wt2a, Wt2b, b2, tb, ub, N, ntiles);
    gather_mean_kernel<64, true><<<(N * 8 + TPB - 1) / TPB, TPB, 0, stream>>>(
        tb, nbrp, cursor, ub, out, N);
}